// Round 3
// baseline (535.067 us; speedup 1.0000x reference)
//
#include <hip/hip_runtime.h>
#include <hip/hip_bf16.h>
#include <stdint.h>

// Problem constants (B=4, S=2048, IN=4096, OUT=4096, FP=256)
// Harness dtype contract (deduced R2): reference float16 tensors are
// delivered/read as FLOAT32 (no fp16 branch in harness decode); int8 -> int32.
#define N_TOK 8192
#define IN_F  4096
#define OUT_F 4096
#define FP_F  256
#define INT_F 3840
#define NGRP  120     // nibble groups of 32 values per row
#define PROW  1920    // packed int4 bytes per row (INT_F/2)

typedef int    v4i   __attribute__((ext_vector_type(4)));
typedef int    v16i  __attribute__((ext_vector_type(16)));
typedef float  v16f  __attribute__((ext_vector_type(16)));
typedef __bf16 bf16x8 __attribute__((ext_vector_type(8)));

// ---------------- workspace layout (bytes) ----------------
#define WS_QP   0u            // [N_TOK][PROW] packed codes c=q+8 in [0,15]
#define WS_WP   15728640u     // [OUT_F][PROW] packed codes w+8 in [0,15]
#define WS_FPX  23592960u     // [N_TOK][FP_F] bf16 gathered outliers
#define WS_WFP  27787264u     // [OUT_F][FP_F] bf16 converted fp_weight
#define WS_SC   29884416u     // [N_TOK] float scale
#define WS_MN   29917184u     // [N_TOK] float row min
#define WS_SUM  29949952u     // [N_TOK] float sum of codes (exact int)
#define WS_NEED 29982720u

// Nibble packing: byte[g*16+b] = code[g*32+b] | (code[g*32+16+b] << 4).
// u32 unpack (u & 0x0F0F0F0F) -> 4 consecutive k codes; (u>>4)&... -> the 4
// codes 16 positions later: one 16B packed read -> two contiguous 16B i8 runs.

// Fallback if workspace too small: zeros (finite absmax beacon, f32 out).
__global__ __launch_bounds__(256) void zero_out_kernel(uint4* __restrict__ o) {
  o[(size_t)blockIdx.x * 256 + threadIdx.x] = uint4{0, 0, 0, 0};
}

// Kernel 1: int32 weights -> biased packed int4 codes (w+8 in [0,15]).
__global__ __launch_bounds__(256) void pack_w_kernel(
    const int* __restrict__ w, uint8_t* __restrict__ wp) {
  int gid = blockIdx.x * 256 + threadIdx.x;      // one thread per 32-value group
  int r = gid / NGRP, g = gid % NGRP;
  const int* src = w + (size_t)r * INT_F + g * 32;
  uint32_t ow[4];
#pragma unroll
  for (int i = 0; i < 4; i++) {
    uint32_t v = 0;
#pragma unroll
    for (int j = 0; j < 4; j++) {
      uint32_t lo = (uint32_t)(src[i * 4 + j] + 8) & 0xFu;
      uint32_t hi = (uint32_t)(src[i * 4 + j + 16] + 8) & 0xFu;
      v |= (lo | (hi << 4)) << (8 * j);
    }
    ow[i] = v;
  }
  uint4 o4; o4.x = ow[0]; o4.y = ow[1]; o4.z = ow[2]; o4.w = ow[3];
  *(uint4*)(wp + (size_t)r * PROW + g * 16) = o4;
}

// Kernel 1b: fp_weight f32 -> bf16 (for the outlier MFMA branch).
__global__ __launch_bounds__(256) void conv_wfp_kernel(
    const float* __restrict__ w, __hip_bfloat16* __restrict__ o) {
  int i = (blockIdx.x * 256 + threadIdx.x) * 4;
  float4 v = *(const float4*)(w + i);
  __hip_bfloat16 b[4] = {__float2bfloat16(v.x), __float2bfloat16(v.y),
                         __float2bfloat16(v.z), __float2bfloat16(v.w)};
  *(uint2*)(o + i) = *(const uint2*)b;
}

// Kernel 2: per-token asymmetric quant (codes in [0,15]) + outlier gather.
// One block (256 threads) per token. x rows are FLOAT32.
__global__ __launch_bounds__(256) void quant_kernel(
    const float* __restrict__ x,
    const int* __restrict__ int_idx, const int* __restrict__ fp_idx,
    uint8_t* __restrict__ qp, __hip_bfloat16* __restrict__ fpx,
    float* __restrict__ scale, float* __restrict__ mnb, float* __restrict__ sumc) {
  __shared__ uint4 rowv[IN_F * 4 / 16];   // 16 KB: whole f32 x row
  __shared__ float smn[4], smx[4], ssum[4], s_mn, s_sc;
  const float* row = (const float*)rowv;

  int n = blockIdx.x, tid = threadIdx.x;
  const uint4* src = (const uint4*)(x + (size_t)n * IN_F);
#pragma unroll
  for (int i = 0; i < 4; i++) rowv[tid + i * 256] = src[tid + i * 256];
  __syncthreads();

  float lmn = 1e30f, lmx = -1e30f;
  for (int i = tid; i < INT_F; i += 256) {
    float v = row[int_idx[i]];
    lmn = fminf(lmn, v);
    lmx = fmaxf(lmx, v);
  }
#pragma unroll
  for (int off = 32; off > 0; off >>= 1) {   // xor butterfly: all lanes valid
    lmn = fminf(lmn, __shfl_xor(lmn, off, 64));
    lmx = fmaxf(lmx, __shfl_xor(lmx, off, 64));
  }
  int wv = tid >> 6, ln = tid & 63;
  if (ln == 0) { smn[wv] = lmn; smx[wv] = lmx; }
  __syncthreads();
  if (tid == 0) {
    float mn = fminf(fminf(smn[0], smn[1]), fminf(smn[2], smn[3]));
    float mx = fmaxf(fmaxf(smx[0], smx[1]), fmaxf(smx[2], smx[3]));
    float sc = fmaxf((mx - mn) / 15.0f, 1e-8f);   // IEEE f32 div, matches ref
    s_mn = mn; s_sc = sc;
    scale[n] = sc; mnb[n] = mn;
  }
  __syncthreads();
  float mn = s_mn, sc = s_sc;

  // pack: thread t < 120 handles group g=t (32 codes -> 16 bytes)
  float lsum = 0.0f;
  if (tid < NGRP) {
    int g = tid;
    uint32_t ow[4];
#pragma unroll
    for (int i = 0; i < 4; i++) {
      uint32_t v = 0;
#pragma unroll
      for (int j = 0; j < 4; j++) {
        int k = g * 32 + i * 4 + j;
        float a = row[int_idx[k]];
        float b = row[int_idx[k + 16]];
        float ca = fminf(fmaxf(rintf((a - mn) / sc), 0.0f), 15.0f);
        float cb = fminf(fmaxf(rintf((b - mn) / sc), 0.0f), 15.0f);
        lsum += ca + cb;
        v |= ((uint32_t)ca | ((uint32_t)cb << 4)) << (8 * j);
      }
      ow[i] = v;
    }
    uint4 o4; o4.x = ow[0]; o4.y = ow[1]; o4.z = ow[2]; o4.w = ow[3];
    *(uint4*)(qp + (size_t)n * PROW + g * 16) = o4;
  }
#pragma unroll
  for (int off = 32; off > 0; off >>= 1) lsum += __shfl_xor(lsum, off, 64);
  if (ln == 0) ssum[wv] = lsum;
  __syncthreads();
  if (tid == 0) sumc[n] = ssum[0] + ssum[1] + ssum[2] + ssum[3];

  // fp outlier gather -> bf16 (FP_F == 256)
  fpx[(size_t)n * FP_F + tid] = __float2bfloat16(row[fp_idx[tid]]);
}

// Kernel 3: fused GEMM. Block tile 128(tok) x 128(out); 4 waves = 2x2
// quadrants of 64x64, each wave 2x2 tiles of 32x32.
// Int phase: 60 k-tiles of K=64, mfma_i32_32x32x32_i8 on unsigned codes.
// bf16 phase: 8 k-tiles of K=32, mfma_f32_32x32x16_bf16.
// LDS per tile: [128 rows][4 segs x 16B], XOR swizzle ss = s ^ (r&3) ^ ((r>>2)&3).
__global__ __launch_bounds__(256, 2) void gemm_kernel(
    const uint8_t* __restrict__ qp, const uint8_t* __restrict__ wp,
    const __hip_bfloat16* __restrict__ fpx, const __hip_bfloat16* __restrict__ wfp,
    const float* __restrict__ scale, const float* __restrict__ mnb,
    const float* __restrict__ sumc,
    const float* __restrict__ wscale, const float* __restrict__ reduced,
    const float* __restrict__ bias, float* __restrict__ out) {
  __shared__ int4 lds4[1024];             // 16 KB: A 8 KB + B 8 KB (unpacked i8)
  int8_t* lds = (int8_t*)lds4;

  int tid = threadIdx.x;
  int wave = tid >> 6, lane = tid & 63;
  int wm = wave >> 1, wn = wave & 1;
  int tileN = blockIdx.x & 31;            // OUT_F/128
  int tileM = blockIdx.x >> 5;            // N_TOK/128
  int n0 = tileM * 128, o0 = tileN * 128;

  v16i acc[2][2];
  v16f accf[2][2];
#pragma unroll
  for (int mi = 0; mi < 2; mi++)
#pragma unroll
    for (int ni = 0; ni < 2; ni++)
#pragma unroll
      for (int e = 0; e < 16; e++) { acc[mi][ni][e] = 0; accf[mi][ni][e] = 0.0f; }

  int m = lane & 31, kg = lane >> 5;
  int sr = tid >> 1, sh = tid & 1;        // staging: row, 16B-half of 32B chunk

  // ---------------- int4 phase ----------------
  for (int kt = 0; kt < 60; kt++) {
    {  // A tile: 16 packed bytes -> two contiguous 16B i8 runs
      uint4 p = *(const uint4*)(qp + (size_t)(n0 + sr) * PROW + kt * 32 + sh * 16);
      uint4 L, H;
      L.x = p.x & 0x0F0F0F0Fu; H.x = (p.x >> 4) & 0x0F0F0F0Fu;
      L.y = p.y & 0x0F0F0F0Fu; H.y = (p.y >> 4) & 0x0F0F0F0Fu;
      L.z = p.z & 0x0F0F0F0Fu; H.z = (p.z >> 4) & 0x0F0F0F0Fu;
      L.w = p.w & 0x0F0F0F0Fu; H.w = (p.w >> 4) & 0x0F0F0F0Fu;
      int sw = (sr & 3) ^ ((sr >> 2) & 3);
      *(uint4*)&lds[(sr * 4 + ((sh * 2) ^ sw)) * 16] = L;
      *(uint4*)&lds[(sr * 4 + ((sh * 2 + 1) ^ sw)) * 16] = H;
    }
    {  // B tile
      uint4 p = *(const uint4*)(wp + (size_t)(o0 + sr) * PROW + kt * 32 + sh * 16);
      uint4 L, H;
      L.x = p.x & 0x0F0F0F0Fu; H.x = (p.x >> 4) & 0x0F0F0F0Fu;
      L.y = p.y & 0x0F0F0F0Fu; H.y = (p.y >> 4) & 0x0F0F0F0Fu;
      L.z = p.z & 0x0F0F0F0Fu; H.z = (p.z >> 4) & 0x0F0F0F0Fu;
      L.w = p.w & 0x0F0F0F0Fu; H.w = (p.w >> 4) & 0x0F0F0F0Fu;
      int sw = (sr & 3) ^ ((sr >> 2) & 3);
      *(uint4*)&lds[8192 + (sr * 4 + ((sh * 2) ^ sw)) * 16] = L;
      *(uint4*)&lds[8192 + (sr * 4 + ((sh * 2 + 1) ^ sw)) * 16] = H;
    }
    __syncthreads();
#pragma unroll
    for (int ks = 0; ks < 2; ks++) {
      v4i a[2], b[2];
#pragma unroll
      for (int mi = 0; mi < 2; mi++) {
        int row = wm * 64 + mi * 32 + m;
        int seg = (ks * 2 + kg) ^ (row & 3) ^ ((row >> 2) & 3);
        a[mi] = *(const v4i*)&lds[(row * 4 + seg) * 16];
      }
#pragma unroll
      for (int ni = 0; ni < 2; ni++) {
        int row = wn * 64 + ni * 32 + m;
        int seg = (ks * 2 + kg) ^ (row & 3) ^ ((row >> 2) & 3);
        b[ni] = *(const v4i*)&lds[8192 + (row * 4 + seg) * 16];
      }
#pragma unroll
      for (int mi = 0; mi < 2; mi++)
#pragma unroll
        for (int ni = 0; ni < 2; ni++)
          acc[mi][ni] = __builtin_amdgcn_mfma_i32_32x32x32_i8(
              a[mi], b[ni], acc[mi][ni], 0, 0, 0);
    }
    __syncthreads();
  }

  // ---------------- bf16 outlier phase ----------------
  const int8_t* fpxb = (const int8_t*)fpx;   // row stride 512 B
  const int8_t* fpwb = (const int8_t*)wfp;   // row stride 512 B
  for (int kt = 0; kt < 8; kt++) {
#pragma unroll
    for (int i = 0; i < 2; i++) {
      int c = tid + i * 256;
      int r = c >> 2, s = c & 3;
      int ss = s ^ (r & 3) ^ ((r >> 2) & 3);
      *(int4*)&lds[(r * 4 + ss) * 16] =
          *(const int4*)(fpxb + (size_t)(n0 + r) * 512 + kt * 64 + s * 16);
    }
#pragma unroll
    for (int i = 0; i < 2; i++) {
      int c = tid + i * 256;
      int r = c >> 2, s = c & 3;
      int ss = s ^ (r & 3) ^ ((r >> 2) & 3);
      *(int4*)&lds[8192 + (r * 4 + ss) * 16] =
          *(const int4*)(fpwb + (size_t)(o0 + r) * 512 + kt * 64 + s * 16);
    }
    __syncthreads();
#pragma unroll
    for (int ks = 0; ks < 2; ks++) {
      bf16x8 a[2], b[2];
#pragma unroll
      for (int mi = 0; mi < 2; mi++) {
        int row = wm * 64 + mi * 32 + m;
        int seg = (ks * 2 + kg) ^ (row & 3) ^ ((row >> 2) & 3);
        a[mi] = *(const bf16x8*)&lds[(row * 4 + seg) * 16];
      }
#pragma unroll
      for (int ni = 0; ni < 2; ni++) {
        int row = wn * 64 + ni * 32 + m;
        int seg = (ks * 2 + kg) ^ (row & 3) ^ ((row >> 2) & 3);
        b[ni] = *(const bf16x8*)&lds[8192 + (row * 4 + seg) * 16];
      }
#pragma unroll
      for (int mi = 0; mi < 2; mi++)
#pragma unroll
        for (int ni = 0; ni < 2; ni++)
          accf[mi][ni] = __builtin_amdgcn_mfma_f32_32x32x16_bf16(
              a[mi], b[ni], accf[mi][ni], 0, 0, 0);
    }
    __syncthreads();
  }

  // ---------------- epilogue (f32 out) ----------------
  // out = (D - 8*sumc[n])*scale[n]*wsc[o] + mn[n]*rw[o] + accf + bias[o]
  // C/D layout: col = lane&31, row = (reg&3) + 8*(reg>>2) + 4*(lane>>5)
  int col = lane & 31, rb = (lane >> 5) * 4;
#pragma unroll
  for (int mi = 0; mi < 2; mi++) {
#pragma unroll
    for (int ni = 0; ni < 2; ni++) {
      int o = o0 + wn * 64 + ni * 32 + col;
      float ws = wscale[o];
      float rw = reduced[o];
      float bs = bias[o];
#pragma unroll
      for (int reg = 0; reg < 16; reg++) {
        int row = (reg & 3) + 8 * (reg >> 2) + rb;
        int n = n0 + wm * 64 + mi * 32 + row;
        float v = ((float)acc[mi][ni][reg] - 8.0f * sumc[n]) * scale[n] * ws
                  + mnb[n] * rw + accf[mi][ni][reg] + bs;
        out[(size_t)n * OUT_F + o] = v;
      }
    }
  }
}

extern "C" void kernel_launch(void* const* d_in, const int* in_sizes, int n_in,
                              void* d_out, int out_size, void* d_ws, size_t ws_size,
                              hipStream_t stream) {
  const float* x     = (const float*)d_in[0];
  const int*   int_w = (const int*)d_in[1];
  const float* fp_w  = (const float*)d_in[2];
  const float* bias  = (const float*)d_in[3];
  const float* wsc   = (const float*)d_in[4];
  const float* red   = (const float*)d_in[5];
  const int*   iidx  = (const int*)d_in[6];
  const int*   fidx  = (const int*)d_in[7];
  float*       out   = (float*)d_out;

  if (ws_size < (size_t)WS_NEED) {
    // diagnostic beacon: finite absmax (~ref magnitude) instead of NaN
    zero_out_kernel<<<out_size / 1024, 256, 0, stream>>>((uint4*)d_out);
    return;
  }

  uint8_t* ws = (uint8_t*)d_ws;
  uint8_t*        qp    = ws + WS_QP;
  uint8_t*        wpk   = ws + WS_WP;
  __hip_bfloat16* fpx   = (__hip_bfloat16*)(ws + WS_FPX);
  __hip_bfloat16* wfp   = (__hip_bfloat16*)(ws + WS_WFP);
  float*          scale = (float*)(ws + WS_SC);
  float*          mnb   = (float*)(ws + WS_MN);
  float*          sumc  = (float*)(ws + WS_SUM);

  pack_w_kernel<<<OUT_F * NGRP / 256, 256, 0, stream>>>(int_w, wpk);
  conv_wfp_kernel<<<OUT_F * FP_F / 4 / 256, 256, 0, stream>>>(fp_w, wfp);
  quant_kernel<<<N_TOK, 256, 0, stream>>>(x, iidx, fidx, qp, fpx, scale, mnb, sumc);
  gemm_kernel<<<(N_TOK / 128) * (OUT_F / 128), 256, 0, stream>>>(
      qp, wpk, fpx, wfp, scale, mnb, sumc, wsc, red, bias, out);
}

// Round 4
// 442.202 us; speedup vs baseline: 1.2100x; 1.2100x over previous
//
#include <hip/hip_runtime.h>
#include <hip/hip_bf16.h>
#include <stdint.h>

// Problem constants (B=4, S=2048, IN=4096, OUT=4096, FP=256)
// Harness dtype contract (verified R3): reference float16 tensors are
// delivered/read as FLOAT32; int8 -> int32; output read as float32.
#define N_TOK 8192
#define IN_F  4096
#define OUT_F 4096
#define FP_F  256
#define INT_F 3840
#define PROW  1920    // packed int4 bytes per row (INT_F/2)

typedef int    v4i   __attribute__((ext_vector_type(4)));
typedef int    v16i  __attribute__((ext_vector_type(16)));
typedef float  v16f  __attribute__((ext_vector_type(16)));
typedef __bf16 bf16x8 __attribute__((ext_vector_type(8)));

// ---------------- workspace layout (bytes) ----------------
#define WS_QP   0u            // [N_TOK][PROW] packed codes c=q+8 in [0,15]
#define WS_WP   15728640u     // [OUT_F][PROW] packed codes w+8 in [0,15]
#define WS_FPX  23592960u     // [N_TOK][FP_F] bf16 gathered outliers
#define WS_WFP  27787264u     // [OUT_F][FP_F] bf16 converted fp_weight
#define WS_F1   29884416u     // [N_TOK] float: scale
#define WS_F2   29917184u     // [N_TOK] float: -8*sumc*scale
#define WS_F3   29949952u     // [N_TOK] float: row min
#define WS_NEED 29982720u

// Group-16 nibble packing (both q and w): for group g (16 codes c[0..15]),
// bytes b[j] = c[j] | (c[j+8]<<4), j<8. One 8B slot == one 16-code MFMA
// fragment; unpack of uint2 u: w0=u.x&M (c0..3), w1=u.y&M (c4..7),
// w2=(u.x>>4)&M (c8..11), w3=(u.y>>4)&M (c12..15), M=0x0F0F0F0F.
// Biased-code algebra: D = sum (q+8)(w+8); out_int = (D - 8*sumc)*sc*ws
// + mn*rw (the 8*sc*rw part of ref's zero*rw is absorbed by biased weights
// since rw = ws*sum(w)). Exact in int32; f32 conversion exact (D < 2^24).

__global__ __launch_bounds__(256) void zero_out_kernel(uint4* __restrict__ o) {
  o[(size_t)blockIdx.x * 256 + threadIdx.x] = uint4{0, 0, 0, 0};
}

// Kernel 1: int32 weights -> biased packed int4 codes, group-16 layout.
__global__ __launch_bounds__(256) void pack_w_kernel(
    const int* __restrict__ w, uint8_t* __restrict__ wp) {
  int gid = blockIdx.x * 256 + threadIdx.x;   // one thread per 32 values
  int r = gid / 120, t = gid % 120;
  const int* src = w + (size_t)r * INT_F + t * 32;
  uint32_t u[4];
#pragma unroll
  for (int h = 0; h < 2; h++) {
    uint32_t a0 = 0, a1 = 0;
#pragma unroll
    for (int j = 0; j < 4; j++) {
      uint32_t lo0 = (uint32_t)(src[h * 16 + j] + 8) & 0xFu;
      uint32_t hi0 = (uint32_t)(src[h * 16 + 8 + j] + 8) & 0xFu;
      a0 |= (lo0 | (hi0 << 4)) << (8 * j);
      uint32_t lo1 = (uint32_t)(src[h * 16 + 4 + j] + 8) & 0xFu;
      uint32_t hi1 = (uint32_t)(src[h * 16 + 12 + j] + 8) & 0xFu;
      a1 |= (lo1 | (hi1 << 4)) << (8 * j);
    }
    u[h * 2] = a0; u[h * 2 + 1] = a1;
  }
  uint4 o4; o4.x = u[0]; o4.y = u[1]; o4.z = u[2]; o4.w = u[3];
  *(uint4*)(wp + (size_t)r * PROW + t * 16) = o4;
}

// Kernel 1b: fp_weight f32 -> bf16.
__global__ __launch_bounds__(256) void conv_wfp_kernel(
    const float* __restrict__ w, __hip_bfloat16* __restrict__ o) {
  int i = (blockIdx.x * 256 + threadIdx.x) * 4;
  float4 v = *(const float4*)(w + i);
  __hip_bfloat16 b[4] = {__float2bfloat16(v.x), __float2bfloat16(v.y),
                         __float2bfloat16(v.z), __float2bfloat16(v.w)};
  *(uint2*)(o + i) = *(const uint2*)b;
}

// Kernel 2: per-token asymmetric quant + outlier gather. One block per token.
// int_indices are SORTED -> direct global gather is nearly coalesced; no row
// staging. Gathered values parked in bank-swizzled LDS for the pack pass.
__global__ __launch_bounds__(256) void quant_kernel(
    const float* __restrict__ x,
    const int* __restrict__ int_idx, const int* __restrict__ fp_idx,
    uint8_t* __restrict__ qp, __hip_bfloat16* __restrict__ fpx,
    float* __restrict__ f1, float* __restrict__ f2, float* __restrict__ f3) {
  __shared__ float gath[INT_F];           // float4-block swizzle b^=((b>>2)&7)
  __shared__ float smn[4], smx[4], ssum[4];
  __shared__ float s_mn, s_sc;

  int n = blockIdx.x, tid = threadIdx.x;
  const float* xr = x + (size_t)n * IN_F;

  float lmn = 1e30f, lmx = -1e30f;
#pragma unroll
  for (int k = 0; k < 15; k++) {
    int i = tid + k * 256;
    float v = xr[int_idx[i]];
    int b = i >> 2;
    gath[(b ^ ((b >> 2) & 7)) * 4 + (i & 3)] = v;
    lmn = fminf(lmn, v);
    lmx = fmaxf(lmx, v);
  }
  // fp outlier gather (independent; overlaps reduction latency)
  fpx[(size_t)n * FP_F + tid] = __float2bfloat16(xr[fp_idx[tid]]);

#pragma unroll
  for (int off = 32; off > 0; off >>= 1) {
    lmn = fminf(lmn, __shfl_xor(lmn, off, 64));
    lmx = fmaxf(lmx, __shfl_xor(lmx, off, 64));
  }
  int wv = tid >> 6, ln = tid & 63;
  if (ln == 0) { smn[wv] = lmn; smx[wv] = lmx; }
  __syncthreads();
  if (tid == 0) {
    float mn = fminf(fminf(smn[0], smn[1]), fminf(smn[2], smn[3]));
    float mx = fmaxf(fmaxf(smx[0], smx[1]), fmaxf(smx[2], smx[3]));
    float sc = fmaxf((mx - mn) / 15.0f, 1e-8f);   // IEEE f32 div, matches ref
    s_mn = mn; s_sc = sc;
    f1[n] = sc; f3[n] = mn;
  }
  __syncthreads();
  float mn = s_mn, sc = s_sc;

  // pack: thread t < 240 handles group g=t (16 codes -> 8 bytes)
  float lsum = 0.0f;
  if (tid < 240) {
    int g = tid;
    const float4* g4 = (const float4*)gath;
    float4 q0 = g4[(g * 4 + 0) ^ (g & 7)];
    float4 q1 = g4[(g * 4 + 1) ^ (g & 7)];
    float4 q2 = g4[(g * 4 + 2) ^ (g & 7)];
    float4 q3 = g4[(g * 4 + 3) ^ (g & 7)];
    float vals[16] = {q0.x, q0.y, q0.z, q0.w, q1.x, q1.y, q1.z, q1.w,
                      q2.x, q2.y, q2.z, q2.w, q3.x, q3.y, q3.z, q3.w};
    uint32_t u0 = 0, u1 = 0;
#pragma unroll
    for (int i = 0; i < 4; i++) {
      float cA = fminf(fmaxf(rintf((vals[i] - mn) / sc), 0.0f), 15.0f);
      float cB = fminf(fmaxf(rintf((vals[i + 8] - mn) / sc), 0.0f), 15.0f);
      float cC = fminf(fmaxf(rintf((vals[i + 4] - mn) / sc), 0.0f), 15.0f);
      float cD = fminf(fmaxf(rintf((vals[i + 12] - mn) / sc), 0.0f), 15.0f);
      lsum += (cA + cB) + (cC + cD);
      u0 |= ((uint32_t)cA | ((uint32_t)cB << 4)) << (8 * i);
      u1 |= ((uint32_t)cC | ((uint32_t)cD << 4)) << (8 * i);
    }
    uint2 o2; o2.x = u0; o2.y = u1;
    *(uint2*)(qp + (size_t)n * PROW + g * 8) = o2;
  }
#pragma unroll
  for (int off = 32; off > 0; off >>= 1) lsum += __shfl_xor(lsum, off, 64);
  if (ln == 0) ssum[wv] = lsum;
  __syncthreads();
  if (tid == 0)
    f2[n] = -8.0f * (ssum[0] + ssum[1] + ssum[2] + ssum[3]) * s_sc;
}

__device__ inline v4i unpack_nib(uint2 u) {
  v4i r;
  r[0] = (int)(u.x & 0x0F0F0F0Fu);
  r[1] = (int)(u.y & 0x0F0F0F0Fu);
  r[2] = (int)((u.x >> 4) & 0x0F0F0F0Fu);
  r[3] = (int)((u.y >> 4) & 0x0F0F0F0Fu);
  return r;
}

// Kernel 3: fused GEMM. Block 128x128, 4 waves in 2x2 quadrants, each wave
// 2x2 tiles of 32x32. Int phase keeps PACKED nibbles in LDS (8B slot = one
// fragment; 24KB LDS traffic/kt vs 291 cyc MFMA -> matrix-pipe bound).
// Single accumulator: int acc converted in-place (exact, <2^24) to f32 with
// the dequant epilogue folded, then bf16 outlier MFMA accumulates on top.
__global__ __launch_bounds__(256, 4) void gemm_kernel(
    const uint8_t* __restrict__ qp, const uint8_t* __restrict__ wp,
    const __hip_bfloat16* __restrict__ fpx, const __hip_bfloat16* __restrict__ wfp,
    const float* __restrict__ f1, const float* __restrict__ f2,
    const float* __restrict__ f3,
    const float* __restrict__ wscale, const float* __restrict__ reduced,
    const float* __restrict__ bias, float* __restrict__ out) {
  __shared__ int4 lds4[1024];             // 16 KB (int phase uses 8 KB)
  int8_t* lds = (int8_t*)lds4;

  int tid = threadIdx.x;
  int wave = tid >> 6, lane = tid & 63;
  int wm = wave >> 1, wn = wave & 1;
  // XCD-aware swizzle: xcd = blk&7 gets an 8-tileM band; within, sweep
  // tileM fastest so the B column + 2MB A band stay hot in that XCD's L2.
  int blk = blockIdx.x;
  int tileM = ((blk & 7) << 3) | ((blk >> 3) & 7);
  int tileN = blk >> 6;
  int n0 = tileM * 128, o0 = tileN * 128;

  union { v16i i; v16f f; } acc[2][2];
#pragma unroll
  for (int mi = 0; mi < 2; mi++)
#pragma unroll
    for (int ni = 0; ni < 2; ni++)
#pragma unroll
      for (int e = 0; e < 16; e++) acc[mi][ni].i[e] = 0;

  int m = lane & 31, kg = lane >> 5;
  int swm = (m & 3) ^ ((m >> 2) & 3);     // fragment-read slot swizzle
  int sr = tid >> 1, sh = tid & 1;        // staging row / 16B half
  int swr = (sr & 3) ^ ((sr >> 2) & 3);   // staging-write slot swizzle
  uint32_t wa0 = (uint32_t)(sr * 4 + ((sh * 2) ^ swr)) * 8;
  uint32_t wa1 = (uint32_t)(sr * 4 + ((sh * 2 + 1) ^ swr)) * 8;
  const uint8_t* ga = qp + (size_t)(n0 + sr) * PROW + sh * 16;
  const uint8_t* gb = wp + (size_t)(o0 + sr) * PROW + sh * 16;

  // ---------------- int4 phase: 60 k-tiles of K=64 ----------------
  uint4 pa = *(const uint4*)ga;
  uint4 pb = *(const uint4*)gb;
  for (int kt = 0; kt < 60; kt++) {
    {  // packed stores: 8B slot = 16-code group
      uint2 t0; t0.x = pa.x; t0.y = pa.y;
      uint2 t1; t1.x = pa.z; t1.y = pa.w;
      *(uint2*)&lds[wa0] = t0;
      *(uint2*)&lds[wa1] = t1;
      uint2 t2; t2.x = pb.x; t2.y = pb.y;
      uint2 t3; t3.x = pb.z; t3.y = pb.w;
      *(uint2*)&lds[4096 + wa0] = t2;
      *(uint2*)&lds[4096 + wa1] = t3;
    }
    __syncthreads();
    if (kt < 59) {  // register prefetch for kt+1, overlaps MFMA below
      pa = *(const uint4*)(ga + (kt + 1) * 32);
      pb = *(const uint4*)(gb + (kt + 1) * 32);
    }
#pragma unroll
    for (int ks = 0; ks < 2; ks++) {
      int slot = (ks * 2 + kg) ^ swm;
      v4i a[2], b[2];
#pragma unroll
      for (int mi = 0; mi < 2; mi++) {
        int row = wm * 64 + mi * 32 + m;
        a[mi] = unpack_nib(*(const uint2*)&lds[row * 32 + slot * 8]);
      }
#pragma unroll
      for (int ni = 0; ni < 2; ni++) {
        int row = wn * 64 + ni * 32 + m;
        b[ni] = unpack_nib(*(const uint2*)&lds[4096 + row * 32 + slot * 8]);
      }
#pragma unroll
      for (int mi = 0; mi < 2; mi++)
#pragma unroll
        for (int ni = 0; ni < 2; ni++)
          acc[mi][ni].i = __builtin_amdgcn_mfma_i32_32x32x32_i8(
              a[mi], b[ni], acc[mi][ni].i, 0, 0, 0);
    }
    __syncthreads();
  }

  // -------- in-place dequant fold: acc.i -> acc.f (exact, D < 2^24) --------
  // val = (D*sc + (-8*sumc*sc)) * ws + mn*rw + bias ; bf16 dot added after.
  int col = lane & 31, rb4 = (lane >> 5) * 4;
  float cws[2], crw[2], cbs[2];
#pragma unroll
  for (int ni = 0; ni < 2; ni++) {
    int o = o0 + wn * 64 + ni * 32 + col;
    cws[ni] = wscale[o]; crw[ni] = reduced[o]; cbs[ni] = bias[o];
  }
#pragma unroll
  for (int mi = 0; mi < 2; mi++) {
#pragma unroll
    for (int reg = 0; reg < 16; reg++) {
      int row = (reg & 3) + 8 * (reg >> 2) + rb4;
      int n = n0 + wm * 64 + mi * 32 + row;
      float a1 = f1[n], a2 = f2[n], a3 = f3[n];
      float d0 = (float)acc[mi][0].i[reg];
      float d1 = (float)acc[mi][1].i[reg];
      acc[mi][0].f[reg] = (d0 * a1 + a2) * cws[0] + a3 * crw[0] + cbs[0];
      acc[mi][1].f[reg] = (d1 * a1 + a2) * cws[1] + a3 * crw[1] + cbs[1];
    }
  }

  // ---------------- bf16 outlier phase: 8 k-tiles of K=32 ----------------
  const int8_t* fpxb = (const int8_t*)fpx;   // row stride 512 B
  const int8_t* fpwb = (const int8_t*)wfp;   // row stride 512 B
  for (int kt = 0; kt < 8; kt++) {
#pragma unroll
    for (int i = 0; i < 2; i++) {
      int c = tid + i * 256;
      int r = c >> 2, s = c & 3;
      int ss = s ^ (r & 3) ^ ((r >> 2) & 3);
      *(int4*)&lds[(r * 4 + ss) * 16] =
          *(const int4*)(fpxb + (size_t)(n0 + r) * 512 + kt * 64 + s * 16);
    }
#pragma unroll
    for (int i = 0; i < 2; i++) {
      int c = tid + i * 256;
      int r = c >> 2, s = c & 3;
      int ss = s ^ (r & 3) ^ ((r >> 2) & 3);
      *(int4*)&lds[8192 + (r * 4 + ss) * 16] =
          *(const int4*)(fpwb + (size_t)(o0 + r) * 512 + kt * 64 + s * 16);
    }
    __syncthreads();
#pragma unroll
    for (int ks = 0; ks < 2; ks++) {
      bf16x8 a[2], b[2];
#pragma unroll
      for (int mi = 0; mi < 2; mi++) {
        int row = wm * 64 + mi * 32 + m;
        int seg = (ks * 2 + kg) ^ (row & 3) ^ ((row >> 2) & 3);
        a[mi] = *(const bf16x8*)&lds[(row * 4 + seg) * 16];
      }
#pragma unroll
      for (int ni = 0; ni < 2; ni++) {
        int row = wn * 64 + ni * 32 + m;
        int seg = (ks * 2 + kg) ^ (row & 3) ^ ((row >> 2) & 3);
        b[ni] = *(const bf16x8*)&lds[8192 + (row * 4 + seg) * 16];
      }
#pragma unroll
      for (int mi = 0; mi < 2; mi++)
#pragma unroll
        for (int ni = 0; ni < 2; ni++)
          acc[mi][ni].f = __builtin_amdgcn_mfma_f32_32x32x16_bf16(
              a[mi], b[ni], acc[mi][ni].f, 0, 0, 0);
    }
    __syncthreads();
  }

  // ---------------- store (f32) ----------------
#pragma unroll
  for (int mi = 0; mi < 2; mi++) {
#pragma unroll
    for (int ni = 0; ni < 2; ni++) {
      int o = o0 + wn * 64 + ni * 32 + col;
#pragma unroll
      for (int reg = 0; reg < 16; reg++) {
        int row = (reg & 3) + 8 * (reg >> 2) + rb4;
        int n = n0 + wm * 64 + mi * 32 + row;
        out[(size_t)n * OUT_F + o] = acc[mi][ni].f[reg];
      }
    }
  }
}

extern "C" void kernel_launch(void* const* d_in, const int* in_sizes, int n_in,
                              void* d_out, int out_size, void* d_ws, size_t ws_size,
                              hipStream_t stream) {
  const float* x     = (const float*)d_in[0];
  const int*   int_w = (const int*)d_in[1];
  const float* fp_w  = (const float*)d_in[2];
  const float* bias  = (const float*)d_in[3];
  const float* wsc   = (const float*)d_in[4];
  const float* red   = (const float*)d_in[5];
  const int*   iidx  = (const int*)d_in[6];
  const int*   fidx  = (const int*)d_in[7];
  float*       out   = (float*)d_out;

  if (ws_size < (size_t)WS_NEED) {
    zero_out_kernel<<<out_size / 1024, 256, 0, stream>>>((uint4*)d_out);
    return;
  }

  uint8_t* ws = (uint8_t*)d_ws;
  uint8_t*        qp  = ws + WS_QP;
  uint8_t*        wpk = ws + WS_WP;
  __hip_bfloat16* fpx = (__hip_bfloat16*)(ws + WS_FPX);
  __hip_bfloat16* wfp = (__hip_bfloat16*)(ws + WS_WFP);
  float*          f1  = (float*)(ws + WS_F1);
  float*          f2  = (float*)(ws + WS_F2);
  float*          f3  = (float*)(ws + WS_F3);

  pack_w_kernel<<<OUT_F * 120 / 256, 256, 0, stream>>>(int_w, wpk);
  conv_wfp_kernel<<<OUT_F * FP_F / 4 / 256, 256, 0, stream>>>(fp_w, wfp);
  quant_kernel<<<N_TOK, 256, 0, stream>>>(x, iidx, fidx, qp, fpx, f1, f2, f3);
  gemm_kernel<<<(N_TOK / 128) * (OUT_F / 128), 256, 0, stream>>>(
      qp, wpk, fpx, wfp, f1, f2, f3, wsc, red, bias, out);
}

// Round 5
// 414.658 us; speedup vs baseline: 1.2904x; 1.0664x over previous
//
#include <hip/hip_runtime.h>
#include <hip/hip_bf16.h>
#include <stdint.h>

// Problem constants (B=4, S=2048, IN=4096, OUT=4096, FP=256)
// Harness dtype contract (verified R3): reference float16 tensors are
// delivered/read as FLOAT32; int8 -> int32; output read as float32.
#define N_TOK 8192
#define IN_F  4096
#define OUT_F 4096
#define FP_F  256
#define INT_F 3840
#define PROW  1920    // packed int4 bytes per row (INT_F/2)

typedef int    v4i   __attribute__((ext_vector_type(4)));
typedef int    v16i  __attribute__((ext_vector_type(16)));
typedef float  v16f  __attribute__((ext_vector_type(16)));
typedef __bf16 bf16x8 __attribute__((ext_vector_type(8)));

// ---------------- workspace layout (bytes) ----------------
#define WS_QP   0u            // [N_TOK][PROW] packed codes c=q+8 in [0,15]
#define WS_WP   15728640u     // [OUT_F][PROW] packed codes w+8 in [0,15]
#define WS_FPX  23592960u     // [N_TOK][FP_F] bf16 gathered outliers
#define WS_WFP  27787264u     // [OUT_F][FP_F] bf16 converted fp_weight
#define WS_F1   29884416u     // [N_TOK] float: scale
#define WS_F2   29917184u     // [N_TOK] float: -8*sumc*scale
#define WS_F3   29949952u     // [N_TOK] float: row min
#define WS_NEED 29982720u

// Group-16 nibble packing (both q and w): group g = 16 codes c[0..15];
// byte j (j<8) = c[j] | (c[j+8]<<4). One 8B slot = one 16-code MFMA fragment.
// unpack uint2 u: {u.x&M, u.y&M, (u.x>>4)&M, (u.y>>4)&M}, M=0x0F0F0F0F.
// Biased-code algebra (verified passing R4): D = sum (q+8)(w+8);
// out = (D*sc + f2)*ws + f3*rw + bias + bf16_outlier_dot,
// f2 = -8*sumc*sc, f3 = mn. Exact in int32; f32 cvt exact (D < 2^24).

__global__ __launch_bounds__(256) void zero_out_kernel(uint4* __restrict__ o) {
  o[(size_t)blockIdx.x * 256 + threadIdx.x] = uint4{0, 0, 0, 0};
}

// Kernel 1: int32 weights -> biased packed int4 codes, group-16 layout.
// One u32 output per thread: two int4 loads (16B, 32B apart) -> 8 nibbles.
__global__ __launch_bounds__(256) void pack_w_kernel(
    const int* __restrict__ w, uint8_t* __restrict__ wp) {
  int t = blockIdx.x * 256 + threadIdx.x;        // u32 index, 4096*480 total
  int r = t / 480, u = t % 480;
  const int* src = w + (size_t)r * INT_F + (u >> 1) * 16 + (u & 1) * 4;
  int4 lo = *(const int4*)src;
  int4 hi = *(const int4*)(src + 8);
  uint32_t o = (uint32_t)((lo.x + 8) & 15) | (uint32_t)((hi.x + 8) & 15) << 4 |
               (uint32_t)((lo.y + 8) & 15) << 8 | (uint32_t)((hi.y + 8) & 15) << 12 |
               (uint32_t)((lo.z + 8) & 15) << 16 | (uint32_t)((hi.z + 8) & 15) << 20 |
               (uint32_t)((lo.w + 8) & 15) << 24 | (uint32_t)((hi.w + 8) & 15) << 28;
  ((uint32_t*)wp)[t] = o;
}

// Kernel 1b: fp_weight f32 -> bf16.
__global__ __launch_bounds__(256) void conv_wfp_kernel(
    const float* __restrict__ w, __hip_bfloat16* __restrict__ o) {
  int i = (blockIdx.x * 256 + threadIdx.x) * 4;
  float4 v = *(const float4*)(w + i);
  __hip_bfloat16 b[4] = {__float2bfloat16(v.x), __float2bfloat16(v.y),
                         __float2bfloat16(v.z), __float2bfloat16(v.w)};
  *(uint2*)(o + i) = *(const uint2*)b;
}

// Kernel 2 v3: one block per token; values live in 15 REGISTERS (no value
// LDS). Coalesced gather (value i = tid+256k), butterfly min/max, quantize
// from registers (reciprocal mul), nibble-pair via shfl_down(8), 1B LDS
// drop, coalesced uint2 store. 3 barriers total.
__global__ __launch_bounds__(256) void quant_kernel(
    const float* __restrict__ x,
    const int* __restrict__ int_idx, const int* __restrict__ fp_idx,
    uint8_t* __restrict__ qp, __hip_bfloat16* __restrict__ fpx,
    float* __restrict__ f1, float* __restrict__ f2, float* __restrict__ f3) {
  __shared__ uint2 qb[240];               // 1920B packed output staging
  __shared__ float smn[4], smx[4], ssum[4];
  __shared__ float s_mn, s_inv, s_sc;

  int n = blockIdx.x, tid = threadIdx.x;
  const float* xr = x + (size_t)n * IN_F;

  float v[15];
  float lmn = 1e30f, lmx = -1e30f;
#pragma unroll
  for (int k = 0; k < 15; k++) {
    v[k] = xr[int_idx[tid + 256 * k]];
    lmn = fminf(lmn, v[k]);
    lmx = fmaxf(lmx, v[k]);
  }
  // fp outlier gather (independent, overlaps reduction)
  fpx[(size_t)n * FP_F + tid] = __float2bfloat16(xr[fp_idx[tid]]);

#pragma unroll
  for (int off = 32; off > 0; off >>= 1) {
    lmn = fminf(lmn, __shfl_xor(lmn, off, 64));
    lmx = fmaxf(lmx, __shfl_xor(lmx, off, 64));
  }
  int wv = tid >> 6, ln = tid & 63;
  if (ln == 0) { smn[wv] = lmn; smx[wv] = lmx; }
  __syncthreads();
  if (tid == 0) {
    float mn = fminf(fminf(smn[0], smn[1]), fminf(smn[2], smn[3]));
    float mx = fmaxf(fmaxf(smx[0], smx[1]), fmaxf(smx[2], smx[3]));
    float sc = fmaxf((mx - mn) / 15.0f, 1e-8f);   // IEEE f32 div, matches ref
    s_mn = mn; s_sc = sc; s_inv = 1.0f / sc;
    f1[n] = sc; f3[n] = mn;
  }
  __syncthreads();
  float mn = s_mn, inv = s_inv;

  uint8_t* qbb = (uint8_t*)qb;
  float lsum = 0.0f;
#pragma unroll
  for (int k = 0; k < 15; k++) {
    // value index i = tid + 256k; code c in [0,15]
    float c = fminf(fmaxf(rintf((v[k] - mn) * inv), 0.0f), 15.0f);
    lsum += c;
    float ch = __shfl_down(c, 8, 64);      // partner value i+8 (same wave)
    if ((tid & 15) < 8) {                  // low-nibble owner writes byte
      qbb[(tid >> 4) * 8 + (tid & 7) + 128 * k] =
          (uint8_t)((uint32_t)c | ((uint32_t)ch << 4));
    }
  }
#pragma unroll
  for (int off = 32; off > 0; off >>= 1) lsum += __shfl_xor(lsum, off, 64);
  if (ln == 0) ssum[wv] = lsum;
  __syncthreads();
  if (tid == 0)
    f2[n] = -8.0f * (ssum[0] + ssum[1] + ssum[2] + ssum[3]) * s_sc;
  if (tid < 240)
    *(uint2*)(qp + (size_t)n * PROW + tid * 8) = qb[tid];
}

__device__ inline v4i unpack_nib(uint2 u) {
  v4i r;
  r[0] = (int)(u.x & 0x0F0F0F0Fu);
  r[1] = (int)(u.y & 0x0F0F0F0Fu);
  r[2] = (int)((u.x >> 4) & 0x0F0F0F0Fu);
  r[3] = (int)((u.y >> 4) & 0x0F0F0F0Fu);
  return r;
}

// Kernel 3 v3: 128x128 block, 4 waves (2x2 quadrants of 64x64, each 2x2
// 32-tiles). Int phase: BK=128 (30 kt, 16 MFMA/wave per barrier window,
// packed nibbles in LDS: A 8KB + B 8KB). bf16 phase: 4 rounds of K=64
// (A 16KB + B 16KB). Swizzles hold every LDS op at its size floor:
//   int  slot8  phys = s8  ^ ((row>>1)&7)   (row stride 64B)
//   bf16 slot16 phys = s16 ^ ((row>>1)&7)   (row stride 128B)
__global__ __launch_bounds__(256, 3) void gemm_kernel(
    const uint8_t* __restrict__ qp, const uint8_t* __restrict__ wp,
    const __hip_bfloat16* __restrict__ fpx, const __hip_bfloat16* __restrict__ wfp,
    const float* __restrict__ f1, const float* __restrict__ f2,
    const float* __restrict__ f3,
    const float* __restrict__ wscale, const float* __restrict__ reduced,
    const float* __restrict__ bias, float* __restrict__ out) {
  __shared__ int4 lds4[2048];             // 32 KB
  int8_t* lds = (int8_t*)lds4;

  int tid = threadIdx.x;
  int wave = tid >> 6, lane = tid & 63;
  int wm = wave >> 1, wn = wave & 1;
  int blk = blockIdx.x;
  int tileM = ((blk & 7) << 3) | ((blk >> 3) & 7);   // XCD-aware swizzle
  int tileN = blk >> 6;
  int n0 = tileM * 128, o0 = tileN * 128;

  union { v16i i; v16f f; } acc[2][2];
#pragma unroll
  for (int mi = 0; mi < 2; mi++)
#pragma unroll
    for (int ni = 0; ni < 2; ni++)
#pragma unroll
      for (int e = 0; e < 16; e++) acc[mi][ni].i[e] = 0;

  int m = lane & 31, kg = lane >> 5;

  // int-phase staging: thread covers chunks tid and tid+256 (16B each);
  // chunk c: row = c>>2, s16 = c&3 (within 64B row)
  int sra = tid >> 2, s16i = tid & 3;
  const uint8_t* ga0 = qp + (size_t)(n0 + sra) * PROW + s16i * 16;
  const uint8_t* ga1 = qp + (size_t)(n0 + sra + 64) * PROW + s16i * 16;
  const uint8_t* gb0 = wp + (size_t)(o0 + sra) * PROW + s16i * 16;
  const uint8_t* gb1 = wp + (size_t)(o0 + sra + 64) * PROW + s16i * 16;
  // LDS write addresses (two 8B slots per 16B chunk)
  uint32_t aw00 = sra * 64 + (((s16i * 2)     ^ ((sra >> 1) & 7)) * 8);
  uint32_t aw01 = sra * 64 + (((s16i * 2 + 1) ^ ((sra >> 1) & 7)) * 8);
  uint32_t aw10 = (sra + 64) * 64 + (((s16i * 2)     ^ (((sra + 64) >> 1) & 7)) * 8);
  uint32_t aw11 = (sra + 64) * 64 + (((s16i * 2 + 1) ^ (((sra + 64) >> 1) & 7)) * 8);

  // ---------------- int4 phase: 30 k-tiles of K=128 ----------------
  uint4 pa0 = *(const uint4*)ga0, pa1 = *(const uint4*)ga1;
  uint4 pb0 = *(const uint4*)gb0, pb1 = *(const uint4*)gb1;
  for (int kt = 0; kt < 30; kt++) {
    {
      uint2 t0; t0.x = pa0.x; t0.y = pa0.y; *(uint2*)&lds[aw00] = t0;
      uint2 t1; t1.x = pa0.z; t1.y = pa0.w; *(uint2*)&lds[aw01] = t1;
      uint2 t2; t2.x = pa1.x; t2.y = pa1.y; *(uint2*)&lds[aw10] = t2;
      uint2 t3; t3.x = pa1.z; t3.y = pa1.w; *(uint2*)&lds[aw11] = t3;
      uint2 t4; t4.x = pb0.x; t4.y = pb0.y; *(uint2*)&lds[8192 + aw00] = t4;
      uint2 t5; t5.x = pb0.z; t5.y = pb0.w; *(uint2*)&lds[8192 + aw01] = t5;
      uint2 t6; t6.x = pb1.x; t6.y = pb1.y; *(uint2*)&lds[8192 + aw10] = t6;
      uint2 t7; t7.x = pb1.z; t7.y = pb1.w; *(uint2*)&lds[8192 + aw11] = t7;
    }
    __syncthreads();
    if (kt < 29) {  // register prefetch for kt+1
      pa0 = *(const uint4*)(ga0 + (kt + 1) * 64);
      pa1 = *(const uint4*)(ga1 + (kt + 1) * 64);
      pb0 = *(const uint4*)(gb0 + (kt + 1) * 64);
      pb1 = *(const uint4*)(gb1 + (kt + 1) * 64);
    }
#pragma unroll
    for (int ks = 0; ks < 4; ks++) {
      int s8 = ks * 2 + kg;
      v4i a[2], b[2];
#pragma unroll
      for (int mi = 0; mi < 2; mi++) {
        int row = wm * 64 + mi * 32 + m;
        a[mi] = unpack_nib(*(const uint2*)&lds[row * 64 + ((s8 ^ ((row >> 1) & 7)) * 8)]);
      }
#pragma unroll
      for (int ni = 0; ni < 2; ni++) {
        int row = wn * 64 + ni * 32 + m;
        b[ni] = unpack_nib(*(const uint2*)&lds[8192 + row * 64 + ((s8 ^ ((row >> 1) & 7)) * 8)]);
      }
#pragma unroll
      for (int mi = 0; mi < 2; mi++)
#pragma unroll
        for (int ni = 0; ni < 2; ni++)
          acc[mi][ni].i = __builtin_amdgcn_mfma_i32_32x32x32_i8(
              a[mi], b[ni], acc[mi][ni].i, 0, 0, 0);
    }
    __syncthreads();
  }

  // -------- in-place dequant fold: acc.i -> acc.f (exact, D < 2^24) --------
  int col = lane & 31, rb4 = (lane >> 5) * 4;
  float cws[2], crw[2], cbs[2];
#pragma unroll
  for (int ni = 0; ni < 2; ni++) {
    int o = o0 + wn * 64 + ni * 32 + col;
    cws[ni] = wscale[o]; crw[ni] = reduced[o]; cbs[ni] = bias[o];
  }
#pragma unroll
  for (int mi = 0; mi < 2; mi++) {
#pragma unroll
    for (int reg = 0; reg < 16; reg++) {
      int row = (reg & 3) + 8 * (reg >> 2) + rb4;
      int n = n0 + wm * 64 + mi * 32 + row;
      float a1 = f1[n], a2 = f2[n], a3 = f3[n];
      float d0 = (float)acc[mi][0].i[reg];
      float d1 = (float)acc[mi][1].i[reg];
      acc[mi][0].f[reg] = (d0 * a1 + a2) * cws[0] + a3 * crw[0] + cbs[0];
      acc[mi][1].f[reg] = (d1 * a1 + a2) * cws[1] + a3 * crw[1] + cbs[1];
    }
  }

  // ---------------- bf16 outlier phase: 4 rounds of K=64 ----------------
  const int8_t* fpxb = (const int8_t*)fpx;   // row stride 512 B
  const int8_t* fpwb = (const int8_t*)wfp;   // row stride 512 B
  for (int kr = 0; kr < 4; kr++) {
#pragma unroll
    for (int i = 0; i < 4; i++) {
      int c = tid + i * 256;
      int row = c >> 3, s16 = c & 7;
      int phys = s16 ^ ((row >> 1) & 7);
      *(int4*)&lds[row * 128 + phys * 16] =
          *(const int4*)(fpxb + (size_t)(n0 + row) * 512 + kr * 128 + s16 * 16);
      *(int4*)&lds[16384 + row * 128 + phys * 16] =
          *(const int4*)(fpwb + (size_t)(o0 + row) * 512 + kr * 128 + s16 * 16);
    }
    __syncthreads();
#pragma unroll
    for (int kstep = 0; kstep < 4; kstep++) {
      int s16 = kstep * 2 + kg;
      bf16x8 a[2], b[2];
#pragma unroll
      for (int mi = 0; mi < 2; mi++) {
        int row = wm * 64 + mi * 32 + m;
        a[mi] = *(const bf16x8*)&lds[row * 128 + ((s16 ^ ((row >> 1) & 7)) * 16)];
      }
#pragma unroll
      for (int ni = 0; ni < 2; ni++) {
        int row = wn * 64 + ni * 32 + m;
        b[ni] = *(const bf16x8*)&lds[16384 + row * 128 + ((s16 ^ ((row >> 1) & 7)) * 16)];
      }
#pragma unroll
      for (int mi = 0; mi < 2; mi++)
#pragma unroll
        for (int ni = 0; ni < 2; ni++)
          acc[mi][ni].f = __builtin_amdgcn_mfma_f32_32x32x16_bf16(
              a[mi], b[ni], acc[mi][ni].f, 0, 0, 0);
    }
    __syncthreads();
  }

  // ---------------- store (f32) ----------------
#pragma unroll
  for (int mi = 0; mi < 2; mi++) {
#pragma unroll
    for (int ni = 0; ni < 2; ni++) {
      int o = o0 + wn * 64 + ni * 32 + col;
#pragma unroll
      for (int reg = 0; reg < 16; reg++) {
        int row = (reg & 3) + 8 * (reg >> 2) + rb4;
        int n = n0 + wm * 64 + mi * 32 + row;
        out[(size_t)n * OUT_F + o] = acc[mi][ni].f[reg];
      }
    }
  }
}

extern "C" void kernel_launch(void* const* d_in, const int* in_sizes, int n_in,
                              void* d_out, int out_size, void* d_ws, size_t ws_size,
                              hipStream_t stream) {
  const float* x     = (const float*)d_in[0];
  const int*   int_w = (const int*)d_in[1];
  const float* fp_w  = (const float*)d_in[2];
  const float* bias  = (const float*)d_in[3];
  const float* wsc   = (const float*)d_in[4];
  const float* red   = (const float*)d_in[5];
  const int*   iidx  = (const int*)d_in[6];
  const int*   fidx  = (const int*)d_in[7];
  float*       out   = (float*)d_out;

  if (ws_size < (size_t)WS_NEED) {
    zero_out_kernel<<<out_size / 1024, 256, 0, stream>>>((uint4*)d_out);
    return;
  }

  uint8_t* ws = (uint8_t*)d_ws;
  uint8_t*        qp  = ws + WS_QP;
  uint8_t*        wpk = ws + WS_WP;
  __hip_bfloat16* fpx = (__hip_bfloat16*)(ws + WS_FPX);
  __hip_bfloat16* wfp = (__hip_bfloat16*)(ws + WS_WFP);
  float*          f1  = (float*)(ws + WS_F1);
  float*          f2  = (float*)(ws + WS_F2);
  float*          f3  = (float*)(ws + WS_F3);

  pack_w_kernel<<<OUT_F * 480 / 256, 256, 0, stream>>>(int_w, wpk);
  conv_wfp_kernel<<<OUT_F * FP_F / 4 / 256, 256, 0, stream>>>(fp_w, wfp);
  quant_kernel<<<N_TOK, 256, 0, stream>>>(x, iidx, fidx, qp, fpx, f1, f2, f3);
  gemm_kernel<<<(N_TOK / 128) * (OUT_F / 128), 256, 0, stream>>>(
      qp, wpk, fpx, wfp, f1, f2, f3, wsc, red, bias, out);
}